// Round 5
// baseline (88.579 us; speedup 1.0000x reference)
//
#include <hip/hip_runtime.h>
#include <hip/hip_bf16.h>

#define M_TOTAL 65536
#define HIDDEN  1024
#define N_TOTAL 152
#define NPAD    160
#define OFF_CLS (M_TOTAL * 8)                  // 524288
#define OFF_REG (OFF_CLS + M_TOTAL * 128)      // 8912896

#define BK      64
#define CHUNK_BYTES (NPAD * BK * 2)            // 20480 per buffer

typedef __attribute__((ext_vector_type(8))) short  bf16x8;
typedef __attribute__((ext_vector_type(4))) float  f32x4;
typedef __attribute__((ext_vector_type(4))) unsigned short u16x4;

__device__ __forceinline__ short bfbits(float f) {
    __hip_bfloat16 h = __float2bfloat16(f);     // RNE; pairs fold to v_cvt_pk_bf16_f32
    return *reinterpret_cast<short*>(&h);
}

// ---- pre-kernel: fuse conf_w/cls_w/reg_w -> bf16 W[160][1024] in ws (rows 152..159 zero) ----
__global__ void convert_w_kernel(const float* __restrict__ conf_w,
                                 const float* __restrict__ cls_w,
                                 const float* __restrict__ reg_w,
                                 unsigned short* __restrict__ wbf) {
    const int r = blockIdx.x;        // 0..159
    const int c = threadIdx.x * 4;   // 256 threads * 4 = 1024
    const float* src;
    if      (r <   8) src = conf_w + (size_t)r * HIDDEN;
    else if (r < 136) src = cls_w  + (size_t)(r -   8) * HIDDEN;
    else if (r < 152) src = reg_w  + (size_t)(r - 136) * HIDDEN;
    else              src = nullptr;
    unsigned short* dst = wbf + (size_t)r * HIDDEN;
    u16x4 o;
    if (src) {
        f32x4 v = *(const f32x4*)(src + c);
        o[0] = (unsigned short)bfbits(v[0]); o[1] = (unsigned short)bfbits(v[1]);
        o[2] = (unsigned short)bfbits(v[2]); o[3] = (unsigned short)bfbits(v[3]);
    } else {
        o[0] = 0; o[1] = 0; o[2] = 0; o[3] = 0;
    }
    *(u16x4*)(dst + c) = o;
}

// stage next B chunk: 5 x global_load_lds (wave-linear dest, XOR-pre-swizzled source)
#define STAGE_B(KOFF, BUFOFF)                                                              \
    _Pragma("unroll")                                                                      \
    for (int i = 0; i < 5; ++i)                                                            \
        __builtin_amdgcn_global_load_lds(                                                  \
            (const __attribute__((address_space(1))) void*)(gstage + (size_t)i * 32 * HIDDEN + (KOFF)), \
            (__attribute__((address_space(3))) void*)(smem + (BUFOFF) + ldsw + i * 4096),  \
            16, 0, 0);

// load one A stage set (2 rows x 1 chunk = 8 f32x4) at k-offset KOFF
#define LOAD_A(S, KOFF)                                                                    \
    do {                                                                                   \
        S[0] = *(const f32x4*)(ap0 + (KOFF));      S[1] = *(const f32x4*)(ap0 + (KOFF) + 4);  \
        S[2] = *(const f32x4*)(ap0 + (KOFF) + 32); S[3] = *(const f32x4*)(ap0 + (KOFF) + 36); \
        S[4] = *(const f32x4*)(ap1 + (KOFF));      S[5] = *(const f32x4*)(ap1 + (KOFF) + 4);  \
        S[6] = *(const f32x4*)(ap1 + (KOFF) + 32); S[7] = *(const f32x4*)(ap1 + (KOFF) + 36); \
    } while (0)

#define CVT1(AF, LO, HI)                                                                   \
    do { _Pragma("unroll")                                                                 \
         for (int j = 0; j < 4; ++j) { AF[j] = bfbits((LO)[j]); AF[4+j] = bfbits((HI)[j]); } \
    } while (0)

// convert a full stage set to the 4 MFMA A-fragments
#define CVT_SET(S)                                                                         \
    do { CVT1(afE0, S[0], S[1]); CVT1(afO0, S[2], S[3]);                                   \
         CVT1(afE1, S[4], S[5]); CVT1(afO1, S[6], S[7]); } while (0)

// one BK=64 chunk: 2 k-steps x 10 N-tiles x 2 row-tiles; each bfrag feeds 2 MFMAs
#define COMPUTE_CHUNK(SB)                                                                  \
    do {                                                                                   \
        bf16x8 bfrag[10];                                                                  \
        _Pragma("unroll")                                                                  \
        for (int nt = 0; nt < 10; ++nt)                                                    \
            bfrag[nt] = *(const bf16x8*)((SB) + rdb0 + nt * 2048);                         \
        _Pragma("unroll")                                                                  \
        for (int nt = 0; nt < 10; ++nt) {                                                  \
            acc0[nt] = __builtin_amdgcn_mfma_f32_16x16x32_bf16(afE0, bfrag[nt], acc0[nt], 0, 0, 0); \
            acc1[nt] = __builtin_amdgcn_mfma_f32_16x16x32_bf16(afE1, bfrag[nt], acc1[nt], 0, 0, 0); \
        }                                                                                  \
        _Pragma("unroll")                                                                  \
        for (int nt = 0; nt < 10; ++nt)                                                    \
            bfrag[nt] = *(const bf16x8*)((SB) + rdb1 + nt * 2048);                         \
        _Pragma("unroll")                                                                  \
        for (int nt = 0; nt < 10; ++nt) {                                                  \
            acc0[nt] = __builtin_amdgcn_mfma_f32_16x16x32_bf16(afO0, bfrag[nt], acc0[nt], 0, 0, 0); \
            acc1[nt] = __builtin_amdgcn_mfma_f32_16x16x32_bf16(afO1, bfrag[nt], acc1[nt], 0, 0, 0); \
        }                                                                                  \
    } while (0)

// ---- main kernel: block = 128 rows (4 waves x 32 rows), all 152 cols.
//      B double-buffered in LDS; counted vmcnt(8) barriers; each LDS bfrag
//      amortized over 2 row-tiles. No launch_bounds VGPR cap. ----
__global__ __launch_bounds__(256) void ssd_mfma_kernel(
    const float* __restrict__ hs,
    const unsigned short* __restrict__ wbf,
    const float* __restrict__ conf_b,
    const float* __restrict__ cls_b,
    const float* __restrict__ reg_b,
    float* __restrict__ out) {

    __shared__ __align__(16) unsigned char smem[2 * CHUNK_BYTES];   // 40 KB

    const int tid  = threadIdx.x;
    const int wave = tid >> 6;
    const int lane = tid & 63;
    const int c    = lane & 15;   // A row-in-tile / B col-in-tile / D col
    const int kg   = lane >> 4;   // k-group 0..3

    const int Rbase = blockIdx.x * 128 + wave * 32;
    const float* ap0 = hs + (size_t)(Rbase +      c) * HIDDEN + kg * 8;
    const float* ap1 = hs + (size_t)(Rbase + 16 + c) * HIDDEN + kg * 8;

    // staging lane constants (write side of the swizzle; rule #21)
    const int srow   = lane >> 3;                 // 0..7
    const int schunk = (lane & 7) ^ srow;         // logical 16B-chunk to fetch
    const unsigned short* gstage =
        wbf + (size_t)(wave * 8 + srow) * HIDDEN + schunk * 8;
    const int ldsw = wave * 1024;                 // wave-uniform LDS base (bytes)

    // read bases (swizzled), bytes within a buffer
    const int rdb0 = c * 128 + ((kg       ^ (c & 7)) * 16);
    const int rdb1 = c * 128 + (((4 | kg) ^ (c & 7)) * 16);

    f32x4 acc0[10], acc1[10];
    #pragma unroll
    for (int nt = 0; nt < 10; ++nt) {
        f32x4 z = {0.f, 0.f, 0.f, 0.f};
        acc0[nt] = z; acc1[nt] = z;
    }

    // -------- prologue: B chunk0 -> buf0; A chunks 0,1 -> named sets --------
    STAGE_B(0, 0);
    f32x4 s0[8], s1[8];
    LOAD_A(s0, 0);
    LOAD_A(s1, 64);
    __builtin_amdgcn_sched_barrier(0);
    asm volatile("s_waitcnt vmcnt(16)");    // B chunk0 done; 16 A loads still in flight
    __builtin_amdgcn_s_barrier();

    bf16x8 afE0, afO0, afE1, afO1;

    // -------- main loop: 7 pairs of chunks, fully pipelined --------
    for (int t = 0; t < 7; ++t) {
        const int kb = t * 128;

        // half 0: compute chunk kb from buf0; stage B(kb+64)->buf1; A(kb+128)->s0
        STAGE_B(kb + 64, CHUNK_BYTES);
        __builtin_amdgcn_sched_barrier(0);
        CVT_SET(s0);
        LOAD_A(s0, kb + 128);
        __builtin_amdgcn_sched_barrier(0);
        COMPUTE_CHUNK(smem);
        __builtin_amdgcn_sched_barrier(0);
        asm volatile("s_waitcnt vmcnt(8)");    // B(kb+64) done; s0 loads stay in flight
        __builtin_amdgcn_s_barrier();

        // half 1: compute chunk kb+64 from buf1; stage B(kb+128)->buf0; A(kb+192)->s1
        STAGE_B(kb + 128, 0);
        __builtin_amdgcn_sched_barrier(0);
        CVT_SET(s1);
        LOAD_A(s1, kb + 192);
        __builtin_amdgcn_sched_barrier(0);
        COMPUTE_CHUNK(smem + CHUNK_BYTES);
        __builtin_amdgcn_sched_barrier(0);
        asm volatile("s_waitcnt vmcnt(8)");    // B(kb+128) done; s1 loads stay in flight
        __builtin_amdgcn_s_barrier();
    }

    // -------- peeled pair 7: chunks 896 (buf0) and 960 (buf1) --------
    STAGE_B(960, CHUNK_BYTES);
    __builtin_amdgcn_sched_barrier(0);
    CVT_SET(s0);                               // chunk 896
    __builtin_amdgcn_sched_barrier(0);
    COMPUTE_CHUNK(smem);
    __builtin_amdgcn_sched_barrier(0);
    asm volatile("s_waitcnt vmcnt(0)");        // the only full drain, once
    __builtin_amdgcn_s_barrier();
    CVT_SET(s1);                               // chunk 960
    COMPUTE_CHUNK(smem + CHUNK_BYTES);

    // -------- epilogue: bias + scatter (D row = kg*4+i, col = nt*16+c) --------
    #pragma unroll
    for (int nt = 0; nt < 10; ++nt) {
        const int n = nt * 16 + c;
        if (n >= N_TOTAL) continue;             // pad cols 152..159
        float bias; size_t obase; int ostride;
        if      (n <   8) { bias = conf_b[n];       obase = (size_t)n;                   ostride = 8;   }
        else if (n < 136) { bias = cls_b[n - 8];    obase = OFF_CLS + (size_t)(n - 8);   ostride = 128; }
        else              { bias = reg_b[n - 136];  obase = OFF_REG + (size_t)(n - 136); ostride = 16;  }
        const int mb0 = Rbase +      kg * 4;
        const int mb1 = Rbase + 16 + kg * 4;
        #pragma unroll
        for (int i = 0; i < 4; ++i) {
            __builtin_nontemporal_store(acc0[nt][i] + bias,
                                        out + obase + (size_t)(mb0 + i) * ostride);
            __builtin_nontemporal_store(acc1[nt][i] + bias,
                                        out + obase + (size_t)(mb1 + i) * ostride);
        }
    }
}

// ---- exact fp32 fallback (only if ws too small; correctness insurance) ----
__global__ void ssd_naive_kernel(const float* __restrict__ hs,
                                 const float* __restrict__ conf_w, const float* __restrict__ conf_b,
                                 const float* __restrict__ cls_w,  const float* __restrict__ cls_b,
                                 const float* __restrict__ reg_w,  const float* __restrict__ reg_b,
                                 float* __restrict__ out) {
    const long long total = (long long)M_TOTAL * N_TOTAL;
    for (long long idx = blockIdx.x * 256LL + threadIdx.x; idx < total;
         idx += (long long)gridDim.x * 256LL) {
        const int m = (int)(idx / N_TOTAL);
        const int n = (int)(idx % N_TOTAL);
        const float* w; float b; size_t o;
        if      (n <   8) { w = conf_w + (size_t)n * HIDDEN;         b = conf_b[n];       o = (size_t)m * 8 + n; }
        else if (n < 136) { w = cls_w + (size_t)(n - 8) * HIDDEN;    b = cls_b[n - 8];    o = OFF_CLS + (size_t)m * 128 + (n - 8); }
        else              { w = reg_w + (size_t)(n - 136) * HIDDEN;  b = reg_b[n - 136];  o = OFF_REG + (size_t)m * 16 + (n - 136); }
        const float* x = hs + (size_t)m * HIDDEN;
        float s = 0.f;
        for (int k = 0; k < HIDDEN; k += 4) {
            f32x4 xv = *(const f32x4*)(x + k);
            f32x4 wv = *(const f32x4*)(w + k);
            s += xv[0] * wv[0] + xv[1] * wv[1] + xv[2] * wv[2] + xv[3] * wv[3];
        }
        out[o] = s + b;
    }
}

extern "C" void kernel_launch(void* const* d_in, const int* in_sizes, int n_in,
                              void* d_out, int out_size, void* d_ws, size_t ws_size,
                              hipStream_t stream) {
    const float* hs     = (const float*)d_in[0];
    const float* conf_w = (const float*)d_in[1];
    const float* conf_b = (const float*)d_in[2];
    const float* cls_w  = (const float*)d_in[3];
    const float* cls_b  = (const float*)d_in[4];
    const float* reg_w  = (const float*)d_in[5];
    const float* reg_b  = (const float*)d_in[6];
    float* out = (float*)d_out;

    const size_t ws_needed = (size_t)NPAD * HIDDEN * sizeof(unsigned short); // 320 KB
    if (d_ws && ws_size >= ws_needed) {
        unsigned short* wbf = (unsigned short*)d_ws;
        convert_w_kernel<<<160, 256, 0, stream>>>(conf_w, cls_w, reg_w, wbf);
        ssd_mfma_kernel<<<M_TOTAL / 128, 256, 0, stream>>>(hs, wbf, conf_b, cls_b, reg_b, out);
    } else {
        ssd_naive_kernel<<<2048, 256, 0, stream>>>(hs, conf_w, conf_b,
                                                   cls_w, cls_b, reg_w, reg_b, out);
    }
}

// Round 6
// 62.479 us; speedup vs baseline: 1.4177x; 1.4177x over previous
//
#include <hip/hip_runtime.h>
#include <hip/hip_bf16.h>

#define M_TOTAL 65536
#define HIDDEN  1024
#define N_TOTAL 152
#define NPAD    160
#define OFF_CLS (M_TOTAL * 8)                  // 524288
#define OFF_REG (OFF_CLS + M_TOTAL * 128)      // 8912896

#define BK      64
#define CHUNK_BYTES (NPAD * BK * 2)            // 20480 per buffer

typedef __attribute__((ext_vector_type(8))) short  bf16x8;
typedef __attribute__((ext_vector_type(4))) float  f32x4;
typedef __attribute__((ext_vector_type(2))) float  f32x2;
typedef __attribute__((ext_vector_type(4))) unsigned short u16x4;

__device__ __forceinline__ short bfbits(float f) {
    __hip_bfloat16 h = __float2bfloat16(f);     // RNE; pairs fold to v_cvt_pk_bf16_f32
    return *reinterpret_cast<short*>(&h);
}

// ---- pre-kernel: fuse conf_w/cls_w/reg_w -> bf16 W[160][1024] in ws (rows 152..159 zero) ----
__global__ void convert_w_kernel(const float* __restrict__ conf_w,
                                 const float* __restrict__ cls_w,
                                 const float* __restrict__ reg_w,
                                 unsigned short* __restrict__ wbf) {
    const int r = blockIdx.x;        // 0..159
    const int c = threadIdx.x * 4;   // 256 threads * 4 = 1024
    const float* src;
    if      (r <   8) src = conf_w + (size_t)r * HIDDEN;
    else if (r < 136) src = cls_w  + (size_t)(r -   8) * HIDDEN;
    else if (r < 152) src = reg_w  + (size_t)(r - 136) * HIDDEN;
    else              src = nullptr;
    unsigned short* dst = wbf + (size_t)r * HIDDEN;
    u16x4 o;
    if (src) {
        f32x4 v = *(const f32x4*)(src + c);
        o[0] = (unsigned short)bfbits(v[0]); o[1] = (unsigned short)bfbits(v[1]);
        o[2] = (unsigned short)bfbits(v[2]); o[3] = (unsigned short)bfbits(v[3]);
    } else {
        o[0] = 0; o[1] = 0; o[2] = 0; o[3] = 0;
    }
    *(u16x4*)(dst + c) = o;
}

// stage one B chunk: 5 x global_load_lds (wave-linear dest, XOR-pre-swizzled source)
#define STAGE_B(KOFF, BUFOFF)                                                              \
    _Pragma("unroll")                                                                      \
    for (int i = 0; i < 5; ++i)                                                            \
        __builtin_amdgcn_global_load_lds(                                                  \
            (const __attribute__((address_space(1))) void*)(gstage + (size_t)i * 32 * HIDDEN + (KOFF)), \
            (__attribute__((address_space(3))) void*)(smem + (BUFOFF) + ldsw + i * 4096),  \
            16, 0, 0);

#define LOAD_A(SA, SB, SC, SD, KOFF)                                                       \
    do { SA = *(const f32x4*)(ap + (KOFF));      SB = *(const f32x4*)(ap + (KOFF) + 4);    \
         SC = *(const f32x4*)(ap + (KOFF) + 32); SD = *(const f32x4*)(ap + (KOFF) + 36); } while (0)

#define CVT(AF, LO, HI)                                                                    \
    do { _Pragma("unroll")                                                                 \
         for (int j = 0; j < 4; ++j) { AF[j] = bfbits((LO)[j]); AF[4+j] = bfbits((HI)[j]); } \
    } while (0)

// one BK=64 chunk: 2 k-steps x 10 N-tiles, reading swizzled LDS buffer at SB
#define COMPUTE_CHUNK(SB)                                                                  \
    do {                                                                                   \
        bf16x8 bfrag[10];                                                                  \
        _Pragma("unroll")                                                                  \
        for (int nt = 0; nt < 10; ++nt)                                                    \
            bfrag[nt] = *(const bf16x8*)((SB) + rdb0 + nt * 2048);                         \
        _Pragma("unroll")                                                                  \
        for (int nt = 0; nt < 10; ++nt)                                                    \
            acc[nt] = __builtin_amdgcn_mfma_f32_16x16x32_bf16(afE, bfrag[nt], acc[nt], 0, 0, 0); \
        _Pragma("unroll")                                                                  \
        for (int nt = 0; nt < 10; ++nt)                                                    \
            bfrag[nt] = *(const bf16x8*)((SB) + rdb1 + nt * 2048);                         \
        _Pragma("unroll")                                                                  \
        for (int nt = 0; nt < 10; ++nt)                                                    \
            acc[nt] = __builtin_amdgcn_mfma_f32_16x16x32_bf16(afO, bfrag[nt], acc[nt], 0, 0, 0); \
    } while (0)

// ---- main kernel: block = 64 rows (4 waves x 16 rows), all 152 cols (round-4 pipeline).
//      NEW: per-block K-rotation (de-convoy) + LDS-bounced coalesced epilogue. ----
__global__ __launch_bounds__(256) void ssd_mfma_kernel(
    const float* __restrict__ hs,
    const unsigned short* __restrict__ wbf,
    const float* __restrict__ conf_b,
    const float* __restrict__ cls_b,
    const float* __restrict__ reg_b,
    float* __restrict__ out) {

    __shared__ __align__(16) unsigned char smem[2 * CHUNK_BYTES];   // 40 KB

    const int tid  = threadIdx.x;
    const int wave = tid >> 6;
    const int lane = tid & 63;
    const int c    = lane & 15;   // A row-in-tile / B col-in-tile / D col
    const int kg   = lane >> 4;   // k-group 0..3

    const int Rbase = blockIdx.x * 64 + wave * 16;
    const float* ap = hs + (size_t)(Rbase + c) * HIDDEN + kg * 8;

    // per-block K-rotation start chunk (de-convoy): golden-ratio hash -> 0..15
    const int p0 = (int)((blockIdx.x * 2654435761u) >> 28);

    // staging lane constants (write side of the swizzle; rule #21)
    const int srow   = lane >> 3;                 // 0..7
    const int schunk = (lane & 7) ^ srow;         // logical 16B-chunk to fetch
    const unsigned short* gstage =
        wbf + (size_t)(wave * 8 + srow) * HIDDEN + schunk * 8;
    const int ldsw = wave * 1024;                 // wave-uniform LDS base (bytes)

    // read bases (swizzled), bytes within a buffer
    const int rdb0 = c * 128 + ((kg       ^ (c & 7)) * 16);
    const int rdb1 = c * 128 + (((4 | kg) ^ (c & 7)) * 16);

    f32x4 acc[10];
    #pragma unroll
    for (int nt = 0; nt < 10; ++nt) {
        f32x4 z = {0.f, 0.f, 0.f, 0.f};
        acc[nt] = z;
    }

    // -------- prologue: B chunk(p0) -> buf0; A chunks p0, p0+1 -> named sets --------
    f32x4 s0a, s0b, s0c, s0d, s1a, s1b, s1c, s1d;
    {
        const int kA = p0 * 64;
        const int kB = ((p0 + 1) & 15) * 64;
        STAGE_B(kA, 0);
        LOAD_A(s0a, s0b, s0c, s0d, kA);
        LOAD_A(s1a, s1b, s1c, s1d, kB);
    }
    __builtin_amdgcn_sched_barrier(0);
    asm volatile("s_waitcnt vmcnt(8)");     // B chunk done; 8 A loads still in flight
    __builtin_amdgcn_s_barrier();

    bf16x8 afE, afO;

    // -------- main loop: 7 pairs of chunks, fully pipelined, K rotated mod 16 --------
    for (int t = 0; t < 7; ++t) {
        const int i0 = 2 * t;
        const int k1 = ((p0 + i0 + 1) & 15) * 64;   // staged in half 0
        const int k2 = ((p0 + i0 + 2) & 15) * 64;   // A prefetch (s0) + staged in half 1
        const int k3 = ((p0 + i0 + 3) & 15) * 64;   // A prefetch (s1)

        // half 0: compute chunk i0 from buf0
        STAGE_B(k1, CHUNK_BYTES);
        __builtin_amdgcn_sched_barrier(0);
        CVT(afE, s0a, s0b); CVT(afO, s0c, s0d);
        LOAD_A(s0a, s0b, s0c, s0d, k2);
        __builtin_amdgcn_sched_barrier(0);
        COMPUTE_CHUNK(smem);
        __builtin_amdgcn_sched_barrier(0);
        asm volatile("s_waitcnt vmcnt(4)");    // B(k1) done; s0 loads stay in flight
        __builtin_amdgcn_s_barrier();

        // half 1: compute chunk i0+1 from buf1
        STAGE_B(k2, 0);
        __builtin_amdgcn_sched_barrier(0);
        CVT(afE, s1a, s1b); CVT(afO, s1c, s1d);
        LOAD_A(s1a, s1b, s1c, s1d, k3);
        __builtin_amdgcn_sched_barrier(0);
        COMPUTE_CHUNK(smem + CHUNK_BYTES);
        __builtin_amdgcn_sched_barrier(0);
        asm volatile("s_waitcnt vmcnt(4)");    // B(k2) done; s1 loads stay in flight
        __builtin_amdgcn_s_barrier();
    }

    // -------- peeled pair 7: chunks p0+14 (buf0) and p0+15 (buf1) --------
    {
        const int k15 = ((p0 + 15) & 15) * 64;
        STAGE_B(k15, CHUNK_BYTES);
    }
    __builtin_amdgcn_sched_barrier(0);
    CVT(afE, s0a, s0b); CVT(afO, s0c, s0d);    // chunk p0+14
    __builtin_amdgcn_sched_barrier(0);
    COMPUTE_CHUNK(smem);
    __builtin_amdgcn_sched_barrier(0);
    asm volatile("s_waitcnt vmcnt(0)");        // the only full drain, once
    __builtin_amdgcn_s_barrier();
    CVT(afE, s1a, s1b); CVT(afO, s1c, s1d);    // chunk p0+15
    COMPUTE_CHUNK(smem + CHUNK_BYTES);

    // -------- epilogue: acc -> LDS (wave-private [16][160] f32, stride 640B),
    //          then lane-linear full-line NT stores per contiguous region --------
    __syncthreads();                            // all waves done reading B buffers
    unsigned char* wb = smem + wave * 10240;

    #pragma unroll
    for (int nt = 0; nt < 10; ++nt) {
        const int n = nt * 16 + c;
        if (n >= N_TOTAL) continue;             // pad cols 152..159 never read back
        const float bias = (n < 8) ? conf_b[n]
                         : (n < 136) ? cls_b[n - 8]
                         : reg_b[n - 136];
        #pragma unroll
        for (int i = 0; i < 4; ++i)
            *(float*)(wb + (kg * 4 + i) * 640 + n * 4) = acc[nt][i] + bias;
    }
    // wave-private region: ds_write -> ds_read ordered by lgkmcnt, no barrier needed

    // conf: rows Rbase..+15 x 8 cols = 512B contiguous
    {
        f32x2 v = *(const f32x2*)(wb + (lane >> 2) * 640 + (lane & 3) * 8);
        __builtin_nontemporal_store(v, (f32x2*)(out + (size_t)Rbase * 8 + lane * 2));
    }
    // cls: 16 x 128 = 8KB contiguous
    #pragma unroll
    for (int j = 0; j < 8; ++j) {
        f32x4 v = *(const f32x4*)(wb + (j * 2 + (lane >> 5)) * 640 + 32 + (lane & 31) * 16);
        __builtin_nontemporal_store(v, (f32x4*)(out + OFF_CLS + (size_t)Rbase * 128 + j * 256 + lane * 4));
    }
    // reg: 16 x 16 = 1KB contiguous
    {
        f32x4 v = *(const f32x4*)(wb + (lane >> 2) * 640 + 544 + (lane & 3) * 16);
        __builtin_nontemporal_store(v, (f32x4*)(out + OFF_REG + (size_t)Rbase * 16 + lane * 4));
    }
}

// ---- exact fp32 fallback (only if ws too small; correctness insurance) ----
__global__ void ssd_naive_kernel(const float* __restrict__ hs,
                                 const float* __restrict__ conf_w, const float* __restrict__ conf_b,
                                 const float* __restrict__ cls_w,  const float* __restrict__ cls_b,
                                 const float* __restrict__ reg_w,  const float* __restrict__ reg_b,
                                 float* __restrict__ out) {
    const long long total = (long long)M_TOTAL * N_TOTAL;
    for (long long idx = blockIdx.x * 256LL + threadIdx.x; idx < total;
         idx += (long long)gridDim.x * 256LL) {
        const int m = (int)(idx / N_TOTAL);
        const int n = (int)(idx % N_TOTAL);
        const float* w; float b; size_t o;
        if      (n <   8) { w = conf_w + (size_t)n * HIDDEN;         b = conf_b[n];       o = (size_t)m * 8 + n; }
        else if (n < 136) { w = cls_w + (size_t)(n - 8) * HIDDEN;    b = cls_b[n - 8];    o = OFF_CLS + (size_t)m * 128 + (n - 8); }
        else              { w = reg_w + (size_t)(n - 136) * HIDDEN;  b = reg_b[n - 136];  o = OFF_REG + (size_t)m * 16 + (n - 136); }
        const float* x = hs + (size_t)m * HIDDEN;
        float s = 0.f;
        for (int k = 0; k < HIDDEN; k += 4) {
            f32x4 xv = *(const f32x4*)(x + k);
            f32x4 wv = *(const f32x4*)(w + k);
            s += xv[0] * wv[0] + xv[1] * wv[1] + xv[2] * wv[2] + xv[3] * wv[3];
        }
        out[o] = s + b;
    }
}

extern "C" void kernel_launch(void* const* d_in, const int* in_sizes, int n_in,
                              void* d_out, int out_size, void* d_ws, size_t ws_size,
                              hipStream_t stream) {
    const float* hs     = (const float*)d_in[0];
    const float* conf_w = (const float*)d_in[1];
    const float* conf_b = (const float*)d_in[2];
    const float* cls_w  = (const float*)d_in[3];
    const float* cls_b  = (const float*)d_in[4];
    const float* reg_w  = (const float*)d_in[5];
    const float* reg_b  = (const float*)d_in[6];
    float* out = (float*)d_out;

    const size_t ws_needed = (size_t)NPAD * HIDDEN * sizeof(unsigned short); // 320 KB
    if (d_ws && ws_size >= ws_needed) {
        unsigned short* wbf = (unsigned short*)d_ws;
        convert_w_kernel<<<160, 256, 0, stream>>>(conf_w, cls_w, reg_w, wbf);
        ssd_mfma_kernel<<<M_TOTAL / 64, 256, 0, stream>>>(hs, wbf, conf_b, cls_b, reg_b, out);
    } else {
        ssd_naive_kernel<<<2048, 256, 0, stream>>>(hs, conf_w, conf_b,
                                                   cls_w, cls_b, reg_w, reg_b, out);
    }
}